// Round 7
// baseline (185.308 us; speedup 1.0000x reference)
//
#include <hip/hip_runtime.h>
#include <hip/hip_bf16.h>

#define NE 32
#define MM 256        // tokens per expert
#define DM 1024       // dmodel
#define ES 2048       // expert size

typedef __attribute__((ext_vector_type(8))) short short8;
typedef __attribute__((ext_vector_type(4))) float f32x4;
typedef unsigned int uint32;
typedef unsigned long long u64;
typedef unsigned short u16;

// One-instruction packed f32->bf16 (RNE). D[15:0]=bf16(a), D[31:16]=bf16(b).
__device__ __forceinline__ uint32 cvt_pk_bf16(float a, float b) {
    uint32 r;
    asm("v_cvt_pk_bf16_f32 %0, %1, %2" : "=v"(r) : "v"(a), "v"(b));
    return r;
}
__device__ __forceinline__ u64 pack4(float a, float b, float c, float d) {
    return (u64)cvt_pk_bf16(a, b) | ((u64)cvt_pk_bf16(c, d) << 32);
}

// Async global->LDS, 16B per lane. LDS dest is wave-uniform base + lane*16.
__device__ __forceinline__ void gl_lds16(const void* g, void* l) {
    __builtin_amdgcn_global_load_lds(
        (const __attribute__((address_space(1))) uint32*)g,
        (__attribute__((address_space(3))) uint32*)l, 16, 0, 0);
}

// B LDS tile: bf16 [n][k], 128B rows, 16B-slot XOR swizzle (verified r1-r6).
__device__ __forceinline__ int b_off(int n, int k) {
    int X = ((n >> 2) & 7) ^ ((n & 3) << 1);
    return n * 128 + ((((k >> 3) ^ X) & 7) << 4) + (((k >> 2) & 1) << 3);
}

// Streaming f32 -> bf16 convert (for x). 16B loads / 8B stores per thread-iter.
__global__ __launch_bounds__(256) void cvt_bf16(const float* __restrict__ x,
                                                u16* __restrict__ xb, int n4) {
    int i = blockIdx.x * blockDim.x + threadIdx.x;
    int stride = gridDim.x * blockDim.x;
    for (; i < n4; i += stride) {
        float4 v = ((const float4*)x)[i];
        ((u64*)xb)[i] = pack4(v.x, v.y, v.z, v.w);
    }
}

// Grouped GEMM: C[e] = act(A[e] @ B[e]) over NE experts.
// Tile 256x256 (BM=256 full expert panel, BN=256): per-step HBM fetch is
// 96KB (A 32 + W 64) covering 2x the output of the r6 tile -- worst-case
// no-L2-reuse traffic drops 1.02GB -> 768MB, W fetched exactly once by
// construction. 512 threads / 8 waves as 2x4, wave-tile 128x64.
// LDS: A 2x32KB + B 2x32KB = 128KB, 1 block/CU. Double-buffered, one
// barrier per K-step. A via global_load_lds w/ source-side granule swizzle;
// B (f32 W) reg-prefetched one step ahead, cvt_pk + 4x4-transposed to LDS.
template<int N, int K, bool RELU, typename CT>
__global__ __launch_bounds__(512) void ec_gemm(
    const u16* __restrict__ A,
    const float* __restrict__ B,
    CT* __restrict__ C)
{
    constexpr int BM = 256, BN = 256, BK = 64;
    constexpr int NT = N / BN;
    constexpr int NSTEP = K / BK;
    constexpr int EPX = NE / 8;   // experts per XCD

    // ---- XCD-aware decode: bid%8 = XCD (hardware round-robin) ----
    int bid   = blockIdx.x;
    int xcd   = bid & 7;
    int local = bid >> 3;
    int e     = xcd * EPX + local / NT;
    int nt    = local % NT;

    const u16*   Ae = A + (size_t)e * MM * K;
    const float* Be = B + (size_t)e * K * N + (size_t)nt * BN;
    CT*          Ce = C + (size_t)e * MM * N + (size_t)nt * BN;

    __shared__ char AsB[2][BM * BK * 2];   // 2 x 32KB bf16, linear (gload dest)
    __shared__ char BsB[2][BN * BK * 2];   // 2 x 32KB bf16 [n][k] swizzled

    const int t    = threadIdx.x;
    const int lane = t & 63;
    const int w    = t >> 6;          // 0..7
    const int wm   = (w >> 2) * 128;  // 2 wave-rows (128 each)
    const int wn   = (w & 3) * 64;    // 4 wave-cols (64 each)
    const int lr   = lane & 15;
    const int lg   = lane >> 4;

    // B staging thread mapping: 512 threads cover 256n x 64k f32 in one pass
    const int bn4 = (t & 63) * 4;     // n quad (0..252)
    const int bkb = (t >> 6) * 8;     // k base (0,8,...,56); two 4-row groups

    f32x4  acc[8][4] = {};
    float4 br[2][4];                  // prefetched B: 2 k-groups x 4 rows

    auto gloadA = [&](int kt, int buf) {
        #pragma unroll
        for (int r = 0; r < 4; ++r) {
            int reg = w * 4 + r;              // 32 x 1KB chunks
            int m   = reg * 8 + (lane >> 3);  // 0..255
            int s   = (lane & 7) ^ (m & 7);
            const u16* g = Ae + (size_t)m * K + kt + s * 8;
            gl_lds16(g, AsB[buf] + reg * 1024);
        }
    };
    auto loadB = [&](int kt) {
        #pragma unroll
        for (int g = 0; g < 2; ++g) {
            const float* Bk = Be + (size_t)(kt + bkb + g * 4) * N + bn4;
            br[g][0] = *(const float4*)(Bk);
            br[g][1] = *(const float4*)(Bk + N);
            br[g][2] = *(const float4*)(Bk + 2 * (size_t)N);
            br[g][3] = *(const float4*)(Bk + 3 * (size_t)N);
        }
    };
    auto writeB = [&](int buf) {
        #pragma unroll
        for (int g = 0; g < 2; ++g) {
            int k4 = bkb + g * 4;
            *(u64*)(BsB[buf] + b_off(bn4 + 0, k4)) = pack4(br[g][0].x, br[g][1].x, br[g][2].x, br[g][3].x);
            *(u64*)(BsB[buf] + b_off(bn4 + 1, k4)) = pack4(br[g][0].y, br[g][1].y, br[g][2].y, br[g][3].y);
            *(u64*)(BsB[buf] + b_off(bn4 + 2, k4)) = pack4(br[g][0].z, br[g][1].z, br[g][2].z, br[g][3].z);
            *(u64*)(BsB[buf] + b_off(bn4 + 3, k4)) = pack4(br[g][0].w, br[g][1].w, br[g][2].w, br[g][3].w);
        }
    };
    auto readA = [&](int i, int k, int buf) -> short8 {
        int m = wm + i * 16 + lr;
        int s = ((k >> 3) ^ (m & 7)) & 7;
        return *(const short8*)(AsB[buf] + m * 128 + s * 16);
    };

    // ---- prologue: stage tile 0 into buf 0 ----
    loadB(0);
    gloadA(0, 0);
    writeB(0);         // waits br via register-dep waitcnt
    __syncthreads();   // drains gloadA (vmcnt) + writeB (lgkm)

    for (int ks = 0; ks < NSTEP; ++ks) {
        const int  c  = ks & 1;
        const bool pf = (ks + 1 < NSTEP);
        // issue next tile's loads FIRST -- in flight across the whole compute
        if (pf) { gloadA((ks + 1) * BK, c ^ 1); loadB((ks + 1) * BK); }

        #pragma unroll
        for (int kk = 0; kk < 2; ++kk) {
            int k = kk * 32 + lg * 8;
            short8 af[8], bfr[4];
            #pragma unroll
            for (int i = 0; i < 8; ++i) af[i] = readA(i, k, c);
            #pragma unroll
            for (int j = 0; j < 4; ++j)
                bfr[j] = *(const short8*)(BsB[c] + b_off(wn + j * 16 + lr, k));
            #pragma unroll
            for (int i = 0; i < 8; ++i)
                #pragma unroll
                for (int j = 0; j < 4; ++j)
                    acc[i][j] = __builtin_amdgcn_mfma_f32_16x16x32_bf16(af[i], bfr[j], acc[i][j], 0, 0, 0);
        }
        // write next B tile to the other buffer (disjoint buf: no barrier needed)
        if (pf) writeB(c ^ 1);
        __syncthreads();   // single barrier per K-step
    }

    // ---- epilogue: C/D layout col=lane&15, row=(lane>>4)*4+reg (verified) ----
    #pragma unroll
    for (int i = 0; i < 8; ++i) {
        #pragma unroll
        for (int rr = 0; rr < 4; ++rr) {
            int row = wm + i * 16 + lg * 4 + rr;
            CT* Cp = Ce + (size_t)row * N + wn + lr;
            if constexpr (sizeof(CT) == 2) {
                #pragma unroll
                for (int jp = 0; jp < 2; ++jp) {
                    float v0 = acc[i][2 * jp + 0][rr];
                    float v1 = acc[i][2 * jp + 1][rr];
                    if constexpr (RELU) {
                        v0 = v0 > 0.0f ? v0 : 0.0f;
                        v1 = v1 > 0.0f ? v1 : 0.0f;
                    }
                    uint32 pk = cvt_pk_bf16(v0, v1);
                    ((u16*)Cp)[(2 * jp + 0) * 16] = (u16)(pk & 0xffffu);
                    ((u16*)Cp)[(2 * jp + 1) * 16] = (u16)(pk >> 16);
                }
            } else {
                #pragma unroll
                for (int j = 0; j < 4; ++j) {
                    float v = acc[i][j][rr];
                    if constexpr (RELU) v = v > 0.0f ? v : 0.0f;
                    ((float*)Cp)[j * 16] = v;
                }
            }
        }
    }
}

extern "C" void kernel_launch(void* const* d_in, const int* in_sizes, int n_in,
                              void* d_out, int out_size, void* d_ws, size_t ws_size,
                              hipStream_t stream) {
    const float* x    = (const float*)d_in[0];
    // d_in[1] = gate: dead code in the reference output -- unused.
    const float* lin1 = (const float*)d_in[2];
    const float* lin2 = (const float*)d_in[3];
    float* out = (float*)d_out;

    u16* h  = (u16*)d_ws;                                     // 33.6 MB bf16
    u16* xb = (u16*)((char*)d_ws + (size_t)36 * 1024 * 1024); // 16.8 MB bf16

    // x: f32 -> bf16 once (bit-identical RNE to per-tile conversion)
    cvt_bf16<<<2048, 256, 0, stream>>>(x, xb, NE * MM * DM / 4);
    // GEMM1: h = relu(x @ W1), per expert 256x2048, K=1024 (256 blocks, 8 waves)
    ec_gemm<ES, DM, true,  u16  ><<<NE * (ES/256), 512, 0, stream>>>(xb, lin1, h);
    // GEMM2: out = h @ W2, per expert 256x1024, K=2048 (128 blocks, 8 waves)
    ec_gemm<DM, ES, false, float><<<NE * (DM/256), 512, 0, stream>>>(h, lin2, out);
}

// Round 8
// 158.750 us; speedup vs baseline: 1.1673x; 1.1673x over previous
//
#include <hip/hip_runtime.h>
#include <hip/hip_bf16.h>

#define NE 32
#define MM 256        // tokens per expert
#define DM 1024       // dmodel
#define ES 2048       // expert size

typedef __attribute__((ext_vector_type(8))) short short8;
typedef __attribute__((ext_vector_type(4))) float f32x4;
typedef unsigned int uint32;
typedef unsigned long long u64;
typedef unsigned short u16;

// One-instruction packed f32->bf16 (RNE). D[15:0]=bf16(a), D[31:16]=bf16(b).
__device__ __forceinline__ uint32 cvt_pk_bf16(float a, float b) {
    uint32 r;
    asm("v_cvt_pk_bf16_f32 %0, %1, %2" : "=v"(r) : "v"(a), "v"(b));
    return r;
}
__device__ __forceinline__ u64 pack4(float a, float b, float c, float d) {
    return (u64)cvt_pk_bf16(a, b) | ((u64)cvt_pk_bf16(c, d) << 32);
}

// Async global->LDS, 16B per lane. LDS dest is wave-uniform base + lane*16.
__device__ __forceinline__ void gl_lds16(const void* g, void* l) {
    __builtin_amdgcn_global_load_lds(
        (const __attribute__((address_space(1))) uint32*)g,
        (__attribute__((address_space(3))) uint32*)l, 16, 0, 0);
}

// B LDS tile: bf16 [n][k], 128B rows, 16B-slot XOR swizzle (verified r1-r7).
__device__ __forceinline__ int b_off(int n, int k) {
    int X = ((n >> 2) & 7) ^ ((n & 3) << 1);
    return n * 128 + ((((k >> 3) ^ X) & 7) << 4) + (((k >> 2) & 1) << 3);
}

// Streaming f32 -> bf16 convert (for x). 16B loads / 8B stores per thread-iter.
__global__ __launch_bounds__(256) void cvt_bf16(const float* __restrict__ x,
                                                u16* __restrict__ xb, int n4) {
    int i = blockIdx.x * blockDim.x + threadIdx.x;
    int stride = gridDim.x * blockDim.x;
    for (; i < n4; i += stride) {
        float4 v = ((const float4*)x)[i];
        ((u64*)xb)[i] = pack4(v.x, v.y, v.z, v.w);
    }
}

// Grouped GEMM: C[e] = act(A[e] @ B[e]) over NE experts.
// BM=256 (full expert panel -> W fetched exactly once by construction).
// BN chosen per-GEMM so grid == 256 == #CUs (no dispatch tail, whole chip):
//   GEMM1: BN=256 (NT=8), GEMM2: BN=128 (NT=8).
// 512 threads / 8 waves; BN=256: 2x4 waves of 128x64 (acc[8][4]);
//                        BN=128: 4x2 waves of  64x64 (acc[4][4]).
// Double-buffered LDS (A 2x32KB + B 2x(BN*128)B), one barrier per K-step.
// A: bf16 via global_load_lds w/ source-side granule swizzle (rule #21).
// B: f32 W, reg-prefetched one step ahead, cvt_pk + 4x4-transposed to LDS.
// XCD decode: all NT blocks of an expert contiguous (bid%8 = XCD heuristic).
template<int N, int K, int BN, bool RELU, typename CT>
__global__ __launch_bounds__(512) void ec_gemm(
    const u16* __restrict__ A,
    const float* __restrict__ B,
    CT* __restrict__ C)
{
    constexpr int BM = 256, BK = 64;
    constexpr int NT = N / BN;
    constexpr int NSTEP = K / BK;
    constexpr int EPX = NE / 8;       // experts per XCD
    constexpr int NG  = BN / 128;     // B-staging k-groups per thread
    constexpr int NQ  = BN / 4;       // n-quads per k-row
    constexpr int WC  = (BN == 256) ? 4 : 2;  // wave cols
    constexpr int MI  = (BN == 256) ? 8 : 4;  // acc rows per wave

    // ---- XCD-aware decode: bid%8 = XCD (hardware round-robin) ----
    int bid   = blockIdx.x;
    int xcd   = bid & 7;
    int local = bid >> 3;
    int e     = xcd * EPX + local / NT;
    int nt    = local % NT;

    const u16*   Ae = A + (size_t)e * MM * K;
    const float* Be = B + (size_t)e * K * N + (size_t)nt * BN;
    CT*          Ce = C + (size_t)e * MM * N + (size_t)nt * BN;

    __shared__ char AsB[2][BM * BK * 2];   // 2 x 32KB bf16, linear (gload dest)
    __shared__ char BsB[2][BN * BK * 2];   // 2 x (BN*128)B bf16 [n][k] swizzled

    const int t    = threadIdx.x;
    const int lane = t & 63;
    const int w    = t >> 6;                    // 0..7
    const int wm   = (w / WC) * (BM / (8 / WC));
    const int wn   = (w % WC) * 64;
    const int lr   = lane & 15;
    const int lg   = lane >> 4;

    // B staging thread mapping: 512 threads cover BN x 64k f32 in one pass
    const int bn4 = (t & (NQ - 1)) * 4;         // n quad
    const int bkb = (t / NQ) * 4 * NG;          // k base

    f32x4  acc[MI][4] = {};
    float4 br[NG][4];                           // prefetched B

    auto gloadA = [&](int kt, int buf) {
        #pragma unroll
        for (int r = 0; r < 4; ++r) {
            int reg = w * 4 + r;              // 32 x 1KB chunks
            int m   = reg * 8 + (lane >> 3);  // 0..255
            int s   = (lane & 7) ^ (m & 7);
            const u16* g = Ae + (size_t)m * K + kt + s * 8;
            gl_lds16(g, AsB[buf] + reg * 1024);
        }
    };
    auto loadB = [&](int kt) {
        #pragma unroll
        for (int g = 0; g < NG; ++g) {
            const float* Bk = Be + (size_t)(kt + bkb + g * 4) * N + bn4;
            br[g][0] = *(const float4*)(Bk);
            br[g][1] = *(const float4*)(Bk + N);
            br[g][2] = *(const float4*)(Bk + 2 * (size_t)N);
            br[g][3] = *(const float4*)(Bk + 3 * (size_t)N);
        }
    };
    auto writeB = [&](int buf) {
        #pragma unroll
        for (int g = 0; g < NG; ++g) {
            int k4 = bkb + g * 4;
            *(u64*)(BsB[buf] + b_off(bn4 + 0, k4)) = pack4(br[g][0].x, br[g][1].x, br[g][2].x, br[g][3].x);
            *(u64*)(BsB[buf] + b_off(bn4 + 1, k4)) = pack4(br[g][0].y, br[g][1].y, br[g][2].y, br[g][3].y);
            *(u64*)(BsB[buf] + b_off(bn4 + 2, k4)) = pack4(br[g][0].z, br[g][1].z, br[g][2].z, br[g][3].z);
            *(u64*)(BsB[buf] + b_off(bn4 + 3, k4)) = pack4(br[g][0].w, br[g][1].w, br[g][2].w, br[g][3].w);
        }
    };
    auto readA = [&](int i, int k, int buf) -> short8 {
        int m = wm + i * 16 + lr;
        int s = ((k >> 3) ^ (m & 7)) & 7;
        return *(const short8*)(AsB[buf] + m * 128 + s * 16);
    };

    // ---- prologue: stage tile 0 into buf 0 ----
    loadB(0);
    gloadA(0, 0);
    writeB(0);         // waits br via register-dep waitcnt
    __syncthreads();   // drains gloadA (vmcnt) + writeB (lgkm)

    for (int ks = 0; ks < NSTEP; ++ks) {
        const int  c  = ks & 1;
        const bool pf = (ks + 1 < NSTEP);
        // issue next tile's loads FIRST -- in flight across the whole compute
        if (pf) { gloadA((ks + 1) * BK, c ^ 1); loadB((ks + 1) * BK); }

        #pragma unroll
        for (int kk = 0; kk < 2; ++kk) {
            int k = kk * 32 + lg * 8;
            short8 af[MI], bfr[4];
            #pragma unroll
            for (int i = 0; i < MI; ++i) af[i] = readA(i, k, c);
            #pragma unroll
            for (int j = 0; j < 4; ++j)
                bfr[j] = *(const short8*)(BsB[c] + b_off(wn + j * 16 + lr, k));
            #pragma unroll
            for (int i = 0; i < MI; ++i)
                #pragma unroll
                for (int j = 0; j < 4; ++j)
                    acc[i][j] = __builtin_amdgcn_mfma_f32_16x16x32_bf16(af[i], bfr[j], acc[i][j], 0, 0, 0);
        }
        // write next B tile to the other buffer (disjoint buf: no barrier needed)
        if (pf) writeB(c ^ 1);
        __syncthreads();   // single barrier per K-step
    }

    // ---- epilogue: C/D layout col=lane&15, row=(lane>>4)*4+reg (verified) ----
    #pragma unroll
    for (int i = 0; i < MI; ++i) {
        #pragma unroll
        for (int rr = 0; rr < 4; ++rr) {
            int row = wm + i * 16 + lg * 4 + rr;
            CT* Cp = Ce + (size_t)row * N + wn + lr;
            if constexpr (sizeof(CT) == 2) {
                #pragma unroll
                for (int jp = 0; jp < 2; ++jp) {
                    float v0 = acc[i][2 * jp + 0][rr];
                    float v1 = acc[i][2 * jp + 1][rr];
                    if constexpr (RELU) {
                        v0 = v0 > 0.0f ? v0 : 0.0f;
                        v1 = v1 > 0.0f ? v1 : 0.0f;
                    }
                    uint32 pk = cvt_pk_bf16(v0, v1);
                    ((u16*)Cp)[(2 * jp + 0) * 16] = (u16)(pk & 0xffffu);
                    ((u16*)Cp)[(2 * jp + 1) * 16] = (u16)(pk >> 16);
                }
            } else {
                #pragma unroll
                for (int j = 0; j < 4; ++j) {
                    float v = acc[i][j][rr];
                    if constexpr (RELU) v = v > 0.0f ? v : 0.0f;
                    ((float*)Cp)[j * 16] = v;
                }
            }
        }
    }
}

extern "C" void kernel_launch(void* const* d_in, const int* in_sizes, int n_in,
                              void* d_out, int out_size, void* d_ws, size_t ws_size,
                              hipStream_t stream) {
    const float* x    = (const float*)d_in[0];
    // d_in[1] = gate: dead code in the reference output -- unused.
    const float* lin1 = (const float*)d_in[2];
    const float* lin2 = (const float*)d_in[3];
    float* out = (float*)d_out;

    u16* h  = (u16*)d_ws;                                     // 33.6 MB bf16
    u16* xb = (u16*)((char*)d_ws + (size_t)36 * 1024 * 1024); // 16.8 MB bf16

    // x: f32 -> bf16 once (bit-identical RNE to per-tile conversion)
    cvt_bf16<<<2048, 256, 0, stream>>>(x, xb, NE * MM * DM / 4);
    // GEMM1: h = relu(x @ W1), per expert 256x2048, K=1024 (256 blocks)
    ec_gemm<ES, DM, 256, true,  u16  ><<<NE * (ES/256), 512, 0, stream>>>(xb, lin1, h);
    // GEMM2: out = h @ W2, per expert 256x1024, K=2048 (256 blocks)
    ec_gemm<DM, ES, 128, false, float><<<NE * (DM/128), 512, 0, stream>>>(h, lin2, out);
}

// Round 10
// 150.772 us; speedup vs baseline: 1.2291x; 1.0529x over previous
//
#include <hip/hip_runtime.h>
#include <hip/hip_bf16.h>

#define NE 32
#define MM 256        // tokens per expert
#define DM 1024       // dmodel
#define ES 2048       // expert size

typedef __attribute__((ext_vector_type(8))) short short8;
typedef __attribute__((ext_vector_type(4))) float f32x4;
typedef unsigned int uint32;
typedef unsigned long long u64;
typedef unsigned short u16;

// One-instruction packed f32->bf16 (RNE). D[15:0]=bf16(a), D[31:16]=bf16(b).
__device__ __forceinline__ uint32 cvt_pk_bf16(float a, float b) {
    uint32 r;
    asm("v_cvt_pk_bf16_f32 %0, %1, %2" : "=v"(r) : "v"(a), "v"(b));
    return r;
}
__device__ __forceinline__ u64 pack4(float a, float b, float c, float d) {
    return (u64)cvt_pk_bf16(a, b) | ((u64)cvt_pk_bf16(c, d) << 32);
}

// Async global->LDS, 16B per lane. LDS dest is wave-uniform base + lane*16.
__device__ __forceinline__ void gl_lds16(const void* g, void* l) {
    __builtin_amdgcn_global_load_lds(
        (const __attribute__((address_space(1))) uint32*)g,
        (__attribute__((address_space(3))) uint32*)l, 16, 0, 0);
}

// Non-temporal 16B load (ext-vector type -- clang builtin requirement).
// Streamed-once data (weights, x): no-allocate so it does NOT evict the
// LLC-resident shared operands (xb, h).
__device__ __forceinline__ f32x4 nt_load4(const float* p) {
    return __builtin_nontemporal_load((const f32x4*)p);
}

// B LDS tile: bf16 [n][k], 128B rows, 16B-slot XOR swizzle (verified r1-r8).
__device__ __forceinline__ int b_off(int n, int k) {
    int X = ((n >> 2) & 7) ^ ((n & 3) << 1);
    return n * 128 + ((((k >> 3) ^ X) & 7) << 4) + (((k >> 2) & 1) << 3);
}

// Streaming f32 -> bf16 convert (for x). x is read once -> non-temporal;
// xb is re-read by GEMM1 -> default (cacheable) stores.
__global__ __launch_bounds__(256) void cvt_bf16(const float* __restrict__ x,
                                                u16* __restrict__ xb, int n4) {
    int i = blockIdx.x * blockDim.x + threadIdx.x;
    int stride = gridDim.x * blockDim.x;
    for (; i < n4; i += stride) {
        f32x4 v = __builtin_nontemporal_load(&((const f32x4*)x)[i]);
        ((u64*)xb)[i] = pack4(v[0], v[1], v[2], v[3]);
    }
}

// Grouped GEMM: C[e] = act(A[e] @ B[e]) over NE experts.
// BM=256 (full expert panel -> W fetched exactly once by construction).
// BN chosen per-GEMM so grid == 256 == #CUs (no dispatch tail, whole chip):
//   GEMM1: BN=256 (NT=8), GEMM2: BN=128 (NT=8).
// W (f32) loads are NON-TEMPORAL: the 536MB weight stream must not flush the
// LLC, so the 8x-shared A panels (xb/h, 50MB total) stay LLC-resident for the
// duplicate reads. A: bf16 via global_load_lds (default policy, cacheable).
// Double-buffered LDS, one barrier per K-step (verified r3-r8 schedule).
template<int N, int K, int BN, bool RELU, typename CT>
__global__ __launch_bounds__(512) void ec_gemm(
    const u16* __restrict__ A,
    const float* __restrict__ B,
    CT* __restrict__ C)
{
    constexpr int BM = 256, BK = 64;
    constexpr int NT = N / BN;
    constexpr int NSTEP = K / BK;
    constexpr int EPX = NE / 8;       // experts per XCD
    constexpr int NG  = BN / 128;     // B-staging k-groups per thread
    constexpr int NQ  = BN / 4;       // n-quads per k-row
    constexpr int WC  = (BN == 256) ? 4 : 2;  // wave cols
    constexpr int MI  = (BN == 256) ? 8 : 4;  // acc rows per wave

    // ---- XCD-aware decode: bid%8 = XCD (hardware round-robin) ----
    int bid   = blockIdx.x;
    int xcd   = bid & 7;
    int local = bid >> 3;
    int e     = xcd * EPX + local / NT;
    int nt    = local % NT;

    const u16*   Ae = A + (size_t)e * MM * K;
    const float* Be = B + (size_t)e * K * N + (size_t)nt * BN;
    CT*          Ce = C + (size_t)e * MM * N + (size_t)nt * BN;

    __shared__ char AsB[2][BM * BK * 2];   // 2 x 32KB bf16, linear (gload dest)
    __shared__ char BsB[2][BN * BK * 2];   // 2 x (BN*128)B bf16 [n][k] swizzled

    const int t    = threadIdx.x;
    const int lane = t & 63;
    const int w    = t >> 6;                    // 0..7
    const int wm   = (w / WC) * (BM / (8 / WC));
    const int wn   = (w % WC) * 64;
    const int lr   = lane & 15;
    const int lg   = lane >> 4;

    // B staging thread mapping: 512 threads cover BN x 64k f32 in one pass
    const int bn4 = (t & (NQ - 1)) * 4;         // n quad
    const int bkb = (t / NQ) * 4 * NG;          // k base

    f32x4 acc[MI][4] = {};
    f32x4 br[NG][4];                            // prefetched B

    auto gloadA = [&](int kt, int buf) {
        #pragma unroll
        for (int r = 0; r < 4; ++r) {
            int reg = w * 4 + r;              // 32 x 1KB chunks
            int m   = reg * 8 + (lane >> 3);  // 0..255
            int s   = (lane & 7) ^ (m & 7);
            const u16* g = Ae + (size_t)m * K + kt + s * 8;
            gl_lds16(g, AsB[buf] + reg * 1024);
        }
    };
    auto loadB = [&](int kt) {
        #pragma unroll
        for (int g = 0; g < NG; ++g) {
            const float* Bk = Be + (size_t)(kt + bkb + g * 4) * N + bn4;
            br[g][0] = nt_load4(Bk);
            br[g][1] = nt_load4(Bk + N);
            br[g][2] = nt_load4(Bk + 2 * (size_t)N);
            br[g][3] = nt_load4(Bk + 3 * (size_t)N);
        }
    };
    auto writeB = [&](int buf) {
        #pragma unroll
        for (int g = 0; g < NG; ++g) {
            int k4 = bkb + g * 4;
            *(u64*)(BsB[buf] + b_off(bn4 + 0, k4)) = pack4(br[g][0][0], br[g][1][0], br[g][2][0], br[g][3][0]);
            *(u64*)(BsB[buf] + b_off(bn4 + 1, k4)) = pack4(br[g][0][1], br[g][1][1], br[g][2][1], br[g][3][1]);
            *(u64*)(BsB[buf] + b_off(bn4 + 2, k4)) = pack4(br[g][0][2], br[g][1][2], br[g][2][2], br[g][3][2]);
            *(u64*)(BsB[buf] + b_off(bn4 + 3, k4)) = pack4(br[g][0][3], br[g][1][3], br[g][2][3], br[g][3][3]);
        }
    };
    auto readA = [&](int i, int k, int buf) -> short8 {
        int m = wm + i * 16 + lr;
        int s = ((k >> 3) ^ (m & 7)) & 7;
        return *(const short8*)(AsB[buf] + m * 128 + s * 16);
    };

    // ---- prologue: stage tile 0 into buf 0 ----
    loadB(0);
    gloadA(0, 0);
    writeB(0);         // waits br via register-dep waitcnt
    __syncthreads();   // drains gloadA (vmcnt) + writeB (lgkm)

    for (int ks = 0; ks < NSTEP; ++ks) {
        const int  c  = ks & 1;
        const bool pf = (ks + 1 < NSTEP);
        // issue next tile's loads FIRST -- in flight across the whole compute
        if (pf) { gloadA((ks + 1) * BK, c ^ 1); loadB((ks + 1) * BK); }

        #pragma unroll
        for (int kk = 0; kk < 2; ++kk) {
            int k = kk * 32 + lg * 8;
            short8 af[MI], bfr[4];
            #pragma unroll
            for (int i = 0; i < MI; ++i) af[i] = readA(i, k, c);
            #pragma unroll
            for (int j = 0; j < 4; ++j)
                bfr[j] = *(const short8*)(BsB[c] + b_off(wn + j * 16 + lr, k));
            #pragma unroll
            for (int i = 0; i < MI; ++i)
                #pragma unroll
                for (int j = 0; j < 4; ++j)
                    acc[i][j] = __builtin_amdgcn_mfma_f32_16x16x32_bf16(af[i], bfr[j], acc[i][j], 0, 0, 0);
        }
        // write next B tile to the other buffer (disjoint buf: no barrier needed)
        if (pf) writeB(c ^ 1);
        __syncthreads();   // single barrier per K-step
    }

    // ---- epilogue: C/D layout col=lane&15, row=(lane>>4)*4+reg (verified) ----
    // bf16 h: default policy (re-read by GEMM2, keep LLC-resident).
    // f32 out: non-temporal (never re-read).
    #pragma unroll
    for (int i = 0; i < MI; ++i) {
        #pragma unroll
        for (int rr = 0; rr < 4; ++rr) {
            int row = wm + i * 16 + lg * 4 + rr;
            CT* Cp = Ce + (size_t)row * N + wn + lr;
            if constexpr (sizeof(CT) == 2) {
                #pragma unroll
                for (int jp = 0; jp < 2; ++jp) {
                    float v0 = acc[i][2 * jp + 0][rr];
                    float v1 = acc[i][2 * jp + 1][rr];
                    if constexpr (RELU) {
                        v0 = v0 > 0.0f ? v0 : 0.0f;
                        v1 = v1 > 0.0f ? v1 : 0.0f;
                    }
                    uint32 pk = cvt_pk_bf16(v0, v1);
                    ((u16*)Cp)[(2 * jp + 0) * 16] = (u16)(pk & 0xffffu);
                    ((u16*)Cp)[(2 * jp + 1) * 16] = (u16)(pk >> 16);
                }
            } else {
                #pragma unroll
                for (int j = 0; j < 4; ++j) {
                    float v = acc[i][j][rr];
                    if constexpr (RELU) v = v > 0.0f ? v : 0.0f;
                    __builtin_nontemporal_store(v, &((float*)Cp)[j * 16]);
                }
            }
        }
    }
}

extern "C" void kernel_launch(void* const* d_in, const int* in_sizes, int n_in,
                              void* d_out, int out_size, void* d_ws, size_t ws_size,
                              hipStream_t stream) {
    const float* x    = (const float*)d_in[0];
    // d_in[1] = gate: dead code in the reference output -- unused.
    const float* lin1 = (const float*)d_in[2];
    const float* lin2 = (const float*)d_in[3];
    float* out = (float*)d_out;

    u16* h  = (u16*)d_ws;                                     // 33.6 MB bf16
    u16* xb = (u16*)((char*)d_ws + (size_t)36 * 1024 * 1024); // 16.8 MB bf16

    // x: f32 -> bf16 once (bit-identical RNE to per-tile conversion)
    cvt_bf16<<<2048, 256, 0, stream>>>(x, xb, NE * MM * DM / 4);
    // GEMM1: h = relu(x @ W1), per expert 256x2048, K=1024 (256 blocks)
    ec_gemm<ES, DM, 256, true,  u16  ><<<NE * (ES/256), 512, 0, stream>>>(xb, lin1, h);
    // GEMM2: out = h @ W2, per expert 256x1024, K=2048 (256 blocks)
    ec_gemm<DM, ES, 128, false, float><<<NE * (DM/128), 512, 0, stream>>>(h, lin2, out);
}